// Round 12
// baseline (451.161 us; speedup 1.0000x reference)
//
#include <hip/hip_runtime.h>
#include <hip/hip_cooperative_groups.h>

namespace cg = cooperative_groups;

#define NN   12288
#define EE   393216
#define DIN  128
#define DHID 128
#define DOUT 64
#define CAP  96   // bucket capacity; indeg ~ Binom(E,1/N): mean 32, sigma 5.7 -> 96 is ~11 sigma
#define NBC  768  // cooperative grid: 3 blocks/CU x 256 CUs

typedef __attribute__((ext_vector_type(8))) short bf16x8;
typedef __attribute__((ext_vector_type(4))) float f32x4;
typedef __attribute__((ext_vector_type(4))) short s16x4;

// bf16 round-to-nearest-even
__device__ __forceinline__ short f2bf(float f) {
    unsigned u = __float_as_uint(f);
    unsigned r = (u + 0x7fffu + ((u >> 16) & 1u)) >> 16;
    return (short)r;
}
__device__ __forceinline__ float bf2f(short h) {
    return __uint_as_float(((unsigned)(unsigned short)h) << 16);
}

// ================= shared phase bodies =================
__device__ __forceinline__ void gather1_gemm2_node(int c, const float* __restrict__ g1,
                                                   const int* __restrict__ bucket,
                                                   const unsigned* __restrict__ cursor,
                                                   const float* __restrict__ b1,
                                                   const float* __restrict__ W2,
                                                   float* __restrict__ g2,
                                                   float* __restrict__ hrow,  // 128 floats, wave-private
                                                   int lane) {
    const unsigned cnt = cursor[c];
    const float dc = rsqrtf((float)cnt + 1.0f);
    const unsigned e = cnt < CAP ? cnt : CAP;
    const f32x4* __restrict__ G4 = (const f32x4*)g1;  // row r = G4[r*32 .. r*32+31]
    const int* __restrict__ bk = bucket + (size_t)c * CAP;
    const int sub = lane >> 5, col4 = lane & 31;

    f32x4 acc = (f32x4){0.f, 0.f, 0.f, 0.f};
    if (sub == 0) acc = G4[(size_t)c * 32 + col4] * dc;  // self-loop term

    unsigned i = 0;
    int pr[4];
    if (i + 8 <= e) {
#pragma unroll
        for (int p = 0; p < 4; ++p) pr[p] = bk[i + 2 * p + sub];
    }
    for (; i + 8 <= e;) {
        int r[4];
#pragma unroll
        for (int p = 0; p < 4; ++p) r[p] = pr[p];
        const unsigned ni = i + 8;
        if (ni + 8 <= e) {
#pragma unroll
            for (int p = 0; p < 4; ++p) pr[p] = bk[ni + 2 * p + sub];
        }
        float d[4];
        f32x4 v[4];
#pragma unroll
        for (int p = 0; p < 4; ++p) {
            d[p] = rsqrtf((float)cursor[r[p]] + 1.0f);
            v[p] = G4[(size_t)r[p] * 32 + col4];
        }
#pragma unroll
        for (int p = 0; p < 4; ++p) acc += v[p] * d[p];
        i = ni;
    }
    for (; i + 2 <= e; i += 2) {
        int rr = bk[i + sub];
        float d = rsqrtf((float)cursor[rr] + 1.0f);
        acc += G4[(size_t)rr * 32 + col4] * d;
    }
    if (i < e && sub == 0) {
        int rr = bk[i];
        float d = rsqrtf((float)cursor[rr] + 1.0f);
        acc += G4[(size_t)rr * 32 + col4] * d;
    }
    acc.x += __shfl_xor(acc.x, 32);
    acc.y += __shfl_xor(acc.y, 32);
    acc.z += __shfl_xor(acc.z, 32);
    acc.w += __shfl_xor(acc.w, 32);

    f32x4 bb = ((const f32x4*)b1)[col4];
    f32x4 o = acc * dc + bb;
    o.x = fmaxf(o.x, 0.f);
    o.y = fmaxf(o.y, 0.f);
    o.z = fmaxf(o.z, 0.f);
    o.w = fmaxf(o.w, 0.f);
    if (sub == 0) ((f32x4*)hrow)[col4] = o;

    // gemm2: lane computes output column `lane` (wave-private LDS row, no barrier)
    float a2 = 0.f;
#pragma unroll 8
    for (int k = 0; k < DHID; ++k) a2 += hrow[k] * W2[k * DOUT + lane];
    g2[(size_t)c * DOUT + lane] = a2 * dc;
}

__device__ __forceinline__ void gather2_node(int c, const float* __restrict__ g2,
                                             const int* __restrict__ bucket,
                                             const unsigned* __restrict__ cursor,
                                             const float* __restrict__ b2,
                                             short* __restrict__ H, short* __restrict__ Lo,
                                             int lane) {
    const unsigned cnt = cursor[c];
    const float dc = rsqrtf((float)cnt + 1.0f);
    const unsigned e = cnt < CAP ? cnt : CAP;
    const f32x4* __restrict__ G4 = (const f32x4*)g2;  // row r = G4[r*16 .. r*16+15]
    const int* __restrict__ bk = bucket + (size_t)c * CAP;
    const int sub = lane >> 4, col4 = lane & 15;

    f32x4 acc = (f32x4){0.f, 0.f, 0.f, 0.f};
    if (sub == 0) acc = G4[(size_t)c * 16 + col4];  // self (g2 pre-scaled)

    unsigned i = 0;
    int pr0 = 0, pr1 = 0;
    if (i + 8 <= e) { pr0 = bk[i + sub]; pr1 = bk[i + 4 + sub]; }
    for (; i + 8 <= e;) {
        int r0 = pr0, r1 = pr1;
        const unsigned ni = i + 8;
        if (ni + 8 <= e) { pr0 = bk[ni + sub]; pr1 = bk[ni + 4 + sub]; }
        f32x4 v0 = G4[(size_t)r0 * 16 + col4];
        f32x4 v1 = G4[(size_t)r1 * 16 + col4];
        acc += v0;
        acc += v1;
        i = ni;
    }
    for (; i + 4 <= e; i += 4) {
        int rr = bk[i + sub];
        acc += G4[(size_t)rr * 16 + col4];
    }
    if (i < e) {
        if (sub < (int)(e - i)) {
            int rr = bk[i + sub];
            acc += G4[(size_t)rr * 16 + col4];
        }
    }
    acc.x += __shfl_xor(acc.x, 16); acc.x += __shfl_xor(acc.x, 32);
    acc.y += __shfl_xor(acc.y, 16); acc.y += __shfl_xor(acc.y, 32);
    acc.z += __shfl_xor(acc.z, 16); acc.z += __shfl_xor(acc.z, 32);
    acc.w += __shfl_xor(acc.w, 16); acc.w += __shfl_xor(acc.w, 32);

    if (sub == 0) {
        f32x4 bb = ((const f32x4*)b2)[col4];
        f32x4 v = acc * dc + bb;
        s16x4 h4, l4;
        h4.x = f2bf(v.x); l4.x = f2bf(v.x - bf2f(h4.x));
        h4.y = f2bf(v.y); l4.y = f2bf(v.y - bf2f(h4.y));
        h4.z = f2bf(v.z); l4.z = f2bf(v.z - bf2f(h4.z));
        h4.w = f2bf(v.w); l4.w = f2bf(v.w - bf2f(h4.w));
        ((s16x4*)H)[(size_t)c * 16 + col4] = h4;
        ((s16x4*)Lo)[(size_t)c * 16 + col4] = l4;
    }
}

// ================= cooperative mega: zero+fill+gemm1 | gather1+gemm2 | gather2 =================
__global__ __launch_bounds__(256, 3) void k_mega(
    const float* __restrict__ x, const int* __restrict__ row, const int* __restrict__ col,
    const float* __restrict__ W1, const float* __restrict__ b1,
    const float* __restrict__ W2, const float* __restrict__ b2,
    unsigned* __restrict__ cursor, int* __restrict__ bucket,
    float* __restrict__ g1, float* __restrict__ g2,
    short* __restrict__ latH, short* __restrict__ latL) {
    cg::grid_group grid = cg::this_grid();
    const int t = threadIdx.x, b = blockIdx.x;
    const int gid = b * 256 + t;
    const int lane = t & 63, wave = t >> 6;

    __shared__ float smem[16 * DIN];  // 8 KB: gemm1 staging, then hs[4][128]

    // ---- P0: zero cursor ----
    if (gid < NN) cursor[gid] = 0;
    grid.sync();

    // ---- P1: bucket fill (2 edges/thread) + gemm1 (16 rows/block) ----
    {
        int e0 = gid, e1 = gid + NBC * 256;
        int c0 = col[e0], c1 = col[e1];
        unsigned p0 = atomicAdd(&cursor[c0], 1u);
        unsigned p1 = atomicAdd(&cursor[c1], 1u);
        if (p0 < CAP) bucket[(size_t)c0 * CAP + p0] = row[e0];
        if (p1 < CAP) bucket[(size_t)c1 * CAP + p1] = row[e1];
    }
    {
        const int r0 = b * 16;
        for (int j = t; j < 16 * DIN; j += 256) smem[j] = x[(size_t)r0 * DIN + j];
        __syncthreads();
        const int c = t & 127, rg = (t >> 7) * 8;
        float acc[8] = {};
        for (int k = 0; k < DIN; ++k) {
            float w = W1[k * DHID + c];
#pragma unroll
            for (int r = 0; r < 8; ++r) acc[r] += smem[(rg + r) * DIN + k] * w;
        }
#pragma unroll
        for (int r = 0; r < 8; ++r) g1[(size_t)(r0 + rg + r) * DHID + c] = acc[r];
    }
    grid.sync();

    // ---- P2: gather1 + relu + gemm2 (16 nodes/block, 4 per wave) ----
    {
        float* hrow = &smem[wave * DHID];
#pragma unroll
        for (int it = 0; it < 4; ++it)
            gather1_gemm2_node(b * 16 + it * 4 + wave, g1, bucket, cursor, b1, W2, g2, hrow, lane);
    }
    grid.sync();

    // ---- P3: gather2 -> bf16 hi/lo (16 nodes/block) ----
#pragma unroll
    for (int it = 0; it < 4; ++it)
        gather2_node(b * 16 + it * 4 + wave, g2, bucket, cursor, b2, latH, latL, lane);
}

// ================= fallback kernels (R10 path) =================
#define GEMM1_BLOCKS 768
#define FILL_BLOCKS  512
__global__ __launch_bounds__(256) void k_fill_gemm1(const float* __restrict__ x,
                                                    const int* __restrict__ row,
                                                    const int* __restrict__ col,
                                                    const float* __restrict__ W1,
                                                    unsigned* __restrict__ cursor,
                                                    int* __restrict__ bucket,
                                                    float* __restrict__ g1) {
    const int b = blockIdx.x, t = threadIdx.x;
    if (b < GEMM1_BLOCKS) {
        __shared__ float xs[16 * DIN];
        const int r0 = b * 16;
        for (int j = t; j < 16 * DIN; j += 256) xs[j] = x[(size_t)r0 * DIN + j];
        __syncthreads();
        const int c = t & 127, rg = (t >> 7) * 8;
        float acc[8] = {};
        for (int k = 0; k < DIN; ++k) {
            float w = W1[k * DHID + c];
#pragma unroll
            for (int r = 0; r < 8; ++r) acc[r] += xs[(rg + r) * DIN + k] * w;
        }
#pragma unroll
        for (int r = 0; r < 8; ++r) g1[(size_t)(r0 + rg + r) * DHID + c] = acc[r];
    } else {
        const int gid = (b - GEMM1_BLOCKS) * 256 + t;
#pragma unroll
        for (int q = 0; q < 3; ++q) {
            int e = gid + q * (FILL_BLOCKS * 256);
            int c = col[e];
            unsigned p = atomicAdd(&cursor[c], 1u);
            if (p < CAP) bucket[(size_t)c * CAP + p] = row[e];
        }
    }
}

__global__ __launch_bounds__(256) void k_gather1_gemm2(const float* __restrict__ g1,
                                                       const int* __restrict__ bucket,
                                                       const unsigned* __restrict__ cursor,
                                                       const float* __restrict__ b1,
                                                       const float* __restrict__ W2,
                                                       float* __restrict__ g2) {
    __shared__ float hs[4][DHID];
    const int lane = threadIdx.x & 63, wave = threadIdx.x >> 6;
    gather1_gemm2_node(blockIdx.x * 4 + wave, g1, bucket, cursor, b1, W2, g2, hs[wave], lane);
}

__global__ __launch_bounds__(256) void k_gather2(const float* __restrict__ g2,
                                                 const int* __restrict__ bucket,
                                                 const unsigned* __restrict__ cursor,
                                                 const float* __restrict__ b2,
                                                 short* __restrict__ H,
                                                 short* __restrict__ Lo) {
    const int lane = threadIdx.x & 63, wave = threadIdx.x >> 6;
    gather2_node(blockIdx.x * 4 + wave, g2, bucket, cursor, b2, H, Lo, lane);
}

// ---------------- gram: out = latent @ latent^T, symmetric (R10 version) ----------------
#define NTILE 96
#define NPAIR ((NTILE * (NTILE + 1)) / 2)  // 4656
__global__ __launch_bounds__(256) void k_gram(const short* __restrict__ H,
                                              const short* __restrict__ L,
                                              float* __restrict__ out) {
    __shared__ float P[64][132];  // 33.8 KB
    const int tid  = threadIdx.x;
    const int lane = tid & 63;
    const int wave = tid >> 6;

    const int Lb = blockIdx.x;
    int bi = (int)((193.0f - sqrtf(193.0f * 193.0f - 8.0f * (float)Lb)) * 0.5f);
    if (bi < 0) bi = 0;
    if (bi > NTILE - 1) bi = NTILE - 1;
    while (bi * NTILE - (bi * (bi - 1)) / 2 > Lb) --bi;
    while ((bi + 1) * NTILE - ((bi + 1) * bi) / 2 <= Lb) ++bi;
    const int bj = bi + (Lb - (bi * NTILE - (bi * (bi - 1)) / 2));

    const int wm = wave >> 1, wn = wave & 1;
    const int row0 = bi * 128 + wm * 64;
    const int col0 = bj * 128 + wn * 64;
    const int fr = lane & 15;
    const int fk = (lane >> 4) << 3;
    const int crow = (lane >> 4) * 4;
    const bool mirror = (bi != bj);

    bf16x8 aH[4][2], aL[4][2];
#pragma unroll
    for (int m = 0; m < 4; ++m)
#pragma unroll
        for (int k = 0; k < 2; ++k) {
            size_t off = (size_t)(row0 + m * 16 + fr) * DOUT + k * 32 + fk;
            aH[m][k] = *(const bf16x8*)(H + off);
            aL[m][k] = *(const bf16x8*)(L + off);
        }

    f32x4 acc[4][4];  // [n][m]
#pragma unroll
    for (int n = 0; n < 4; ++n)
#pragma unroll
        for (int m = 0; m < 4; ++m) acc[n][m] = (f32x4){0.f, 0.f, 0.f, 0.f};

#pragma unroll
    for (int n = 0; n < 4; ++n) {
        bf16x8 bH[2], bL[2];
#pragma unroll
        for (int k = 0; k < 2; ++k) {
            size_t off = (size_t)(col0 + n * 16 + fr) * DOUT + k * 32 + fk;
            bH[k] = *(const bf16x8*)(H + off);
            bL[k] = *(const bf16x8*)(L + off);
        }
#pragma unroll
        for (int m = 0; m < 4; ++m)
#pragma unroll
            for (int k = 0; k < 2; ++k) {
                acc[n][m] = __builtin_amdgcn_mfma_f32_16x16x32_bf16(aL[m][k], bH[k], acc[n][m], 0, 0, 0);
                acc[n][m] = __builtin_amdgcn_mfma_f32_16x16x32_bf16(aH[m][k], bL[k], acc[n][m], 0, 0, 0);
                acc[n][m] = __builtin_amdgcn_mfma_f32_16x16x32_bf16(aH[m][k], bH[k], acc[n][m], 0, 0, 0);
            }
    }

    const size_t gr0 = (size_t)bi * 128, gc0 = (size_t)bj * 128;
#pragma unroll
    for (int h = 0; h < 2; ++h) {
        __syncthreads();
        if (wm == h) {
#pragma unroll
            for (int n = 0; n < 4; ++n)
#pragma unroll
                for (int m = 0; m < 4; ++m)
#pragma unroll
                    for (int j = 0; j < 4; ++j)
                        P[m * 16 + crow + j][wn * 64 + n * 16 + fr] = acc[n][m][j];
        }
        __syncthreads();
#pragma unroll
        for (int it = 0; it < 8; ++it) {
            int idx = it * 256 + tid;
            int r = idx >> 5, c4 = (idx & 31) << 2;
            f32x4 v = *(const f32x4*)&P[r][c4];
            __builtin_nontemporal_store(v, (f32x4*)&out[(gr0 + h * 64 + r) * NN + gc0 + c4]);
        }
        if (mirror) {
#pragma unroll
            for (int it = 0; it < 8; ++it) {
                int idx = it * 256 + tid;
                int r = idx >> 4, c4 = (idx & 15) << 2;
                f32x4 v;
                v.x = P[c4 + 0][r];
                v.y = P[c4 + 1][r];
                v.z = P[c4 + 2][r];
                v.w = P[c4 + 3][r];
                __builtin_nontemporal_store(v, (f32x4*)&out[(gc0 + r) * NN + gr0 + h * 64 + c4]);
            }
        }
    }
}

extern "C" void kernel_launch(void* const* d_in, const int* in_sizes, int n_in,
                              void* d_out, int out_size, void* d_ws, size_t ws_size,
                              hipStream_t stream) {
    const float* x  = (const float*)d_in[0];
    const int*   ei = (const int*)d_in[1];   // row = ei[0..E), col = ei[E..2E)
    const float* W1 = (const float*)d_in[2];
    const float* b1 = (const float*)d_in[3];
    const float* W2 = (const float*)d_in[4];
    const float* b2 = (const float*)d_in[5];
    float* out = (float*)d_out;

    const int* row = ei;
    const int* col = ei + EE;

    // workspace layout (all 16B aligned)
    char* w = (char*)d_ws;
    unsigned* cursor = (unsigned*)w; w += (size_t)NN * 4;
    int*      bucket = (int*)w;      w += (size_t)NN * CAP * 4;   // 4.5 MB
    float*    g1     = (float*)w;    w += (size_t)NN * DHID * 4;  // 6.3 MB
    float*    g2     = (float*)w;    w += (size_t)NN * DOUT * 4;  // 3.1 MB
    short*    latH   = (short*)w;    w += (size_t)NN * DOUT * 2;  // 1.5 MB
    short*    latL   = (short*)w;    w += (size_t)NN * DOUT * 2;  // 1.5 MB

    void* args[] = {(void*)&x, (void*)&row, (void*)&col, (void*)&W1, (void*)&b1,
                    (void*)&W2, (void*)&b2, (void*)&cursor, (void*)&bucket,
                    (void*)&g1, (void*)&g2, (void*)&latH, (void*)&latL};
    hipError_t err = hipLaunchCooperativeKernel((const void*)k_mega, dim3(NBC), dim3(256),
                                                args, 0, stream);
    if (err != hipSuccess) {
        (void)hipGetLastError();  // clear sticky error
        hipMemsetAsync(cursor, 0, (size_t)NN * 4, stream);
        k_fill_gemm1<<<GEMM1_BLOCKS + FILL_BLOCKS, 256, 0, stream>>>(x, row, col, W1, cursor, bucket, g1);
        k_gather1_gemm2<<<NN / 4, 256, 0, stream>>>(g1, bucket, cursor, b1, W2, g2);
        k_gather2<<<NN / 4, 256, 0, stream>>>(g2, bucket, cursor, b2, latH, latL);
    }

    k_gram<<<NPAIR, 256, 0, stream>>>(latH, latL, out);
}

// Round 13
// 210.876 us; speedup vs baseline: 2.1395x; 2.1395x over previous
//
#include <hip/hip_runtime.h>

#define NN   12288
#define EE   393216
#define DIN  128
#define DHID 128
#define DOUT 64
#define CAP  96   // bucket capacity; indeg ~ Binom(E,1/N): mean 32, sigma 5.7 -> 96 is ~11 sigma

typedef __attribute__((ext_vector_type(8))) short bf16x8;
typedef __attribute__((ext_vector_type(4))) float f32x4;
typedef __attribute__((ext_vector_type(4))) short s16x4;

// bf16 round-to-nearest-even
__device__ __forceinline__ short f2bf(float f) {
    unsigned u = __float_as_uint(f);
    unsigned r = (u + 0x7fffu + ((u >> 16) & 1u)) >> 16;
    return (short)r;
}
__device__ __forceinline__ float bf2f(short h) {
    return __uint_as_float(((unsigned)(unsigned short)h) << 16);
}

// ---------------- K1: fused bucket-fill + raw gemm1 (g1 = x @ W1) ----------------
#define GEMM1_BLOCKS 768
#define FILL_BLOCKS  512
__global__ __launch_bounds__(256) void k_fill_gemm1(const float* __restrict__ x,
                                                    const int* __restrict__ row,
                                                    const int* __restrict__ col,
                                                    const float* __restrict__ W1,
                                                    unsigned* __restrict__ cursor,
                                                    int* __restrict__ bucket,
                                                    float* __restrict__ g1) {
    const int b = blockIdx.x, t = threadIdx.x;
    if (b < GEMM1_BLOCKS) {
        __shared__ float xs[16 * DIN];  // 8 KB
        const int r0 = b * 16;
        for (int j = t; j < 16 * DIN; j += 256) xs[j] = x[(size_t)r0 * DIN + j];
        __syncthreads();
        const int c = t & 127, rg = (t >> 7) * 8;
        float acc[8] = {};
        for (int k = 0; k < DIN; ++k) {
            float w = W1[k * DHID + c];
#pragma unroll
            for (int r = 0; r < 8; ++r) acc[r] += xs[(rg + r) * DIN + k] * w;
        }
#pragma unroll
        for (int r = 0; r < 8; ++r) g1[(size_t)(r0 + rg + r) * DHID + c] = acc[r];
    } else {
        const int gid = (b - GEMM1_BLOCKS) * 256 + t;
#pragma unroll
        for (int q = 0; q < 3; ++q) {
            int e = gid + q * (FILL_BLOCKS * 256);
            int c = col[e];
            unsigned p = atomicAdd(&cursor[c], 1u);
            if (p < CAP) bucket[(size_t)c * CAP + p] = row[e];
        }
    }
}

// ---------------- K2: gather1 + relu + fused gemm2 ----------------
// wave per node (4/block). float4/lane, 2 rows/instr; index prefetch pipeline.
__global__ __launch_bounds__(256) void k_gather1_gemm2(const float* __restrict__ g1,
                                                       const int* __restrict__ bucket,
                                                       const unsigned* __restrict__ cursor,
                                                       const float* __restrict__ b1,
                                                       const float* __restrict__ W2,
                                                       float* __restrict__ g2) {
    __shared__ float hs[4][DHID];  // 2 KB, wave-private rows
    const int lane = threadIdx.x & 63, wave = threadIdx.x >> 6;
    const int c = blockIdx.x * 4 + wave;
    const unsigned cnt = cursor[c];
    const float dc = rsqrtf((float)cnt + 1.0f);
    const unsigned e = cnt < CAP ? cnt : CAP;
    const f32x4* __restrict__ G4 = (const f32x4*)g1;  // row r = G4[r*32 .. r*32+31]
    const int* __restrict__ bk = bucket + (size_t)c * CAP;
    const int sub = lane >> 5, col4 = lane & 31;

    f32x4 acc = (f32x4){0.f, 0.f, 0.f, 0.f};
    if (sub == 0) acc = G4[(size_t)c * 32 + col4] * dc;  // self-loop term

    unsigned i = 0;
    int pr[4];
    if (i + 8 <= e) {
#pragma unroll
        for (int p = 0; p < 4; ++p) pr[p] = bk[i + 2 * p + sub];
    }
    for (; i + 8 <= e;) {
        int r[4];
#pragma unroll
        for (int p = 0; p < 4; ++p) r[p] = pr[p];
        const unsigned ni = i + 8;
        if (ni + 8 <= e) {
#pragma unroll
            for (int p = 0; p < 4; ++p) pr[p] = bk[ni + 2 * p + sub];
        }
        float d[4];
        f32x4 v[4];
#pragma unroll
        for (int p = 0; p < 4; ++p) {
            d[p] = rsqrtf((float)cursor[r[p]] + 1.0f);
            v[p] = G4[(size_t)r[p] * 32 + col4];
        }
#pragma unroll
        for (int p = 0; p < 4; ++p) acc += v[p] * d[p];
        i = ni;
    }
    for (; i + 2 <= e; i += 2) {
        int rr = bk[i + sub];
        float d = rsqrtf((float)cursor[rr] + 1.0f);
        acc += G4[(size_t)rr * 32 + col4] * d;
    }
    if (i < e && sub == 0) {
        int rr = bk[i];
        float d = rsqrtf((float)cursor[rr] + 1.0f);
        acc += G4[(size_t)rr * 32 + col4] * d;
    }
    acc.x += __shfl_xor(acc.x, 32);
    acc.y += __shfl_xor(acc.y, 32);
    acc.z += __shfl_xor(acc.z, 32);
    acc.w += __shfl_xor(acc.w, 32);

    f32x4 bb = ((const f32x4*)b1)[col4];
    f32x4 o = acc * dc + bb;
    o.x = fmaxf(o.x, 0.f);
    o.y = fmaxf(o.y, 0.f);
    o.z = fmaxf(o.z, 0.f);
    o.w = fmaxf(o.w, 0.f);
    if (sub == 0) ((f32x4*)hs[wave])[col4] = o;

    // gemm2: lane computes output column `lane` (wave-private LDS, no barrier;
    // W2 is 32KB and L1-resident after first pass)
    float a2 = 0.f;
#pragma unroll 8
    for (int k = 0; k < DHID; ++k) a2 += hs[wave][k] * W2[k * DOUT + lane];
    g2[(size_t)c * DOUT + lane] = a2 * dc;
}

// ---------------- K3: gather2 -> latent -> bf16 hi/lo ----------------
// wave per node; float4/lane, 4 rows/instr; index prefetch pipeline.
__global__ __launch_bounds__(256) void k_gather2(const float* __restrict__ g2,
                                                 const int* __restrict__ bucket,
                                                 const unsigned* __restrict__ cursor,
                                                 const float* __restrict__ b2,
                                                 short* __restrict__ H,
                                                 short* __restrict__ Lo) {
    const int lane = threadIdx.x & 63, wave = threadIdx.x >> 6;
    const int c = blockIdx.x * 4 + wave;
    const unsigned cnt = cursor[c];
    const float dc = rsqrtf((float)cnt + 1.0f);
    const unsigned e = cnt < CAP ? cnt : CAP;
    const f32x4* __restrict__ G4 = (const f32x4*)g2;  // row r = G4[r*16 .. r*16+15]
    const int* __restrict__ bk = bucket + (size_t)c * CAP;
    const int sub = lane >> 4, col4 = lane & 15;

    f32x4 acc = (f32x4){0.f, 0.f, 0.f, 0.f};
    if (sub == 0) acc = G4[(size_t)c * 16 + col4];  // self (g2 pre-scaled)

    unsigned i = 0;
    int pr0 = 0, pr1 = 0;
    if (i + 8 <= e) { pr0 = bk[i + sub]; pr1 = bk[i + 4 + sub]; }
    for (; i + 8 <= e;) {
        int r0 = pr0, r1 = pr1;
        const unsigned ni = i + 8;
        if (ni + 8 <= e) { pr0 = bk[ni + sub]; pr1 = bk[ni + 4 + sub]; }
        f32x4 v0 = G4[(size_t)r0 * 16 + col4];
        f32x4 v1 = G4[(size_t)r1 * 16 + col4];
        acc += v0;
        acc += v1;
        i = ni;
    }
    for (; i + 4 <= e; i += 4) {
        int rr = bk[i + sub];
        acc += G4[(size_t)rr * 16 + col4];
    }
    if (i < e) {
        if (sub < (int)(e - i)) {
            int rr = bk[i + sub];
            acc += G4[(size_t)rr * 16 + col4];
        }
    }
    acc.x += __shfl_xor(acc.x, 16); acc.x += __shfl_xor(acc.x, 32);
    acc.y += __shfl_xor(acc.y, 16); acc.y += __shfl_xor(acc.y, 32);
    acc.z += __shfl_xor(acc.z, 16); acc.z += __shfl_xor(acc.z, 32);
    acc.w += __shfl_xor(acc.w, 16); acc.w += __shfl_xor(acc.w, 32);

    if (sub == 0) {
        f32x4 bb = ((const f32x4*)b2)[col4];
        f32x4 v = acc * dc + bb;
        s16x4 h4, l4;
        h4.x = f2bf(v.x); l4.x = f2bf(v.x - bf2f(h4.x));
        h4.y = f2bf(v.y); l4.y = f2bf(v.y - bf2f(h4.y));
        h4.z = f2bf(v.z); l4.z = f2bf(v.z - bf2f(h4.z));
        h4.w = f2bf(v.w); l4.w = f2bf(v.w - bf2f(h4.w));
        ((s16x4*)H)[(size_t)c * 16 + col4] = h4;
        ((s16x4*)Lo)[(size_t)c * 16 + col4] = l4;
    }
}

// ---------------- K4: out = latent @ latent^T, symmetric ----------------
// acc in regs; two 64-row stage+store passes (P = 33.8 KB); pinned 3 blocks/CU.
#define NTILE 96
#define NPAIR ((NTILE * (NTILE + 1)) / 2)  // 4656
__global__ __launch_bounds__(256, 3) void k_gram(const short* __restrict__ H,
                                                 const short* __restrict__ L,
                                                 float* __restrict__ out) {
    __shared__ float P[64][132];  // 33.8 KB; rows 16B-aligned
    const int tid  = threadIdx.x;
    const int lane = tid & 63;
    const int wave = tid >> 6;

    // triangular decode: linear Lb -> (bi, bj), bi <= bj
    const int Lb = blockIdx.x;
    int bi = (int)((193.0f - sqrtf(193.0f * 193.0f - 8.0f * (float)Lb)) * 0.5f);
    if (bi < 0) bi = 0;
    if (bi > NTILE - 1) bi = NTILE - 1;
    while (bi * NTILE - (bi * (bi - 1)) / 2 > Lb) --bi;
    while ((bi + 1) * NTILE - ((bi + 1) * bi) / 2 <= Lb) ++bi;
    const int bj = bi + (Lb - (bi * NTILE - (bi * (bi - 1)) / 2));

    const int wm = wave >> 1, wn = wave & 1;
    const int row0 = bi * 128 + wm * 64;
    const int col0 = bj * 128 + wn * 64;
    const int fr = lane & 15;
    const int fk = (lane >> 4) << 3;
    const int crow = (lane >> 4) * 4;
    const bool mirror = (bi != bj);

    bf16x8 aH[4][2], aL[4][2];
#pragma unroll
    for (int m = 0; m < 4; ++m)
#pragma unroll
        for (int k = 0; k < 2; ++k) {
            size_t off = (size_t)(row0 + m * 16 + fr) * DOUT + k * 32 + fk;
            aH[m][k] = *(const bf16x8*)(H + off);
            aL[m][k] = *(const bf16x8*)(L + off);
        }

    f32x4 acc[4][4];  // [n][m]
#pragma unroll
    for (int n = 0; n < 4; ++n)
#pragma unroll
        for (int m = 0; m < 4; ++m) acc[n][m] = (f32x4){0.f, 0.f, 0.f, 0.f};

#pragma unroll
    for (int n = 0; n < 4; ++n) {
        bf16x8 bH[2], bL[2];
#pragma unroll
        for (int k = 0; k < 2; ++k) {
            size_t off = (size_t)(col0 + n * 16 + fr) * DOUT + k * 32 + fk;
            bH[k] = *(const bf16x8*)(H + off);
            bL[k] = *(const bf16x8*)(L + off);
        }
#pragma unroll
        for (int m = 0; m < 4; ++m)
#pragma unroll
            for (int k = 0; k < 2; ++k) {
                acc[n][m] = __builtin_amdgcn_mfma_f32_16x16x32_bf16(aL[m][k], bH[k], acc[n][m], 0, 0, 0);
                acc[n][m] = __builtin_amdgcn_mfma_f32_16x16x32_bf16(aH[m][k], bL[k], acc[n][m], 0, 0, 0);
                acc[n][m] = __builtin_amdgcn_mfma_f32_16x16x32_bf16(aH[m][k], bH[k], acc[n][m], 0, 0, 0);
            }
    }

    const size_t gr0 = (size_t)bi * 128, gc0 = (size_t)bj * 128;
#pragma unroll
    for (int h = 0; h < 2; ++h) {
        __syncthreads();  // protect P reuse across halves
        if (wm == h) {
#pragma unroll
            for (int n = 0; n < 4; ++n)
#pragma unroll
                for (int m = 0; m < 4; ++m)
#pragma unroll
                    for (int j = 0; j < 4; ++j)
                        P[m * 16 + crow + j][wn * 64 + n * 16 + fr] = acc[n][m][j];
        }
        __syncthreads();
        // direct: 64 rows x 128 cols, full 512B rows
#pragma unroll
        for (int it = 0; it < 8; ++it) {
            int idx = it * 256 + tid;
            int r = idx >> 5, c4 = (idx & 31) << 2;
            f32x4 v = *(const f32x4*)&P[r][c4];
            __builtin_nontemporal_store(v, (f32x4*)&out[(gr0 + h * 64 + r) * NN + gc0 + c4]);
        }
        if (mirror) {
            // transposed: 128 rows x 64 cols (256B runs)
#pragma unroll
            for (int it = 0; it < 8; ++it) {
                int idx = it * 256 + tid;
                int r = idx >> 4, c4 = (idx & 15) << 2;
                f32x4 v;
                v.x = P[c4 + 0][r];
                v.y = P[c4 + 1][r];
                v.z = P[c4 + 2][r];
                v.w = P[c4 + 3][r];
                __builtin_nontemporal_store(v, (f32x4*)&out[(gc0 + r) * NN + gr0 + h * 64 + c4]);
            }
        }
    }
}

extern "C" void kernel_launch(void* const* d_in, const int* in_sizes, int n_in,
                              void* d_out, int out_size, void* d_ws, size_t ws_size,
                              hipStream_t stream) {
    const float* x  = (const float*)d_in[0];
    const int*   ei = (const int*)d_in[1];   // row = ei[0..E), col = ei[E..2E)
    const float* W1 = (const float*)d_in[2];
    const float* b1 = (const float*)d_in[3];
    const float* W2 = (const float*)d_in[4];
    const float* b2 = (const float*)d_in[5];
    float* out = (float*)d_out;

    const int* row = ei;
    const int* col = ei + EE;

    // workspace layout (all 16B aligned)
    char* w = (char*)d_ws;
    unsigned* cursor = (unsigned*)w; w += (size_t)NN * 4;
    int*      bucket = (int*)w;      w += (size_t)NN * CAP * 4;   // 4.5 MB
    float*    g1     = (float*)w;    w += (size_t)NN * DHID * 4;  // 6.3 MB
    float*    g2     = (float*)w;    w += (size_t)NN * DOUT * 4;  // 3.1 MB
    short*    latH   = (short*)w;    w += (size_t)NN * DOUT * 2;  // 1.5 MB
    short*    latL   = (short*)w;    w += (size_t)NN * DOUT * 2;  // 1.5 MB

    hipMemsetAsync(cursor, 0, (size_t)NN * 4, stream);

    k_fill_gemm1<<<GEMM1_BLOCKS + FILL_BLOCKS, 256, 0, stream>>>(x, row, col, W1, cursor, bucket, g1);
    k_gather1_gemm2<<<NN / 4, 256, 0, stream>>>(g1, bucket, cursor, b1, W2, g2);
    k_gather2<<<NN / 4, 256, 0, stream>>>(g2, bucket, cursor, b2, latH, latL);

    k_gram<<<NPAIR, 256, 0, stream>>>(latH, latL, out);
}

// Round 14
// 208.924 us; speedup vs baseline: 2.1595x; 1.0093x over previous
//
#include <hip/hip_runtime.h>

#define NN   12288
#define EE   393216
#define DIN  128
#define DHID 128
#define DOUT 64
#define CAP  96   // bucket capacity; indeg ~ Binom(E,1/N): mean 32, sigma 5.7 -> 96 is ~11 sigma

typedef __attribute__((ext_vector_type(8))) short bf16x8;
typedef __attribute__((ext_vector_type(4))) float f32x4;
typedef __attribute__((ext_vector_type(4))) short s16x4;

// bf16 round-to-nearest-even
__device__ __forceinline__ short f2bf(float f) {
    unsigned u = __float_as_uint(f);
    unsigned r = (u + 0x7fffu + ((u >> 16) & 1u)) >> 16;
    return (short)r;
}
__device__ __forceinline__ float bf2f(short h) {
    return __uint_as_float(((unsigned)(unsigned short)h) << 16);
}

// ---------------- K1: fused bucket-fill + raw gemm1 (g1 = x @ W1) ----------------
#define GEMM1_BLOCKS 768
#define FILL_BLOCKS  512
__global__ __launch_bounds__(256) void k_fill_gemm1(const float* __restrict__ x,
                                                    const int* __restrict__ row,
                                                    const int* __restrict__ col,
                                                    const float* __restrict__ W1,
                                                    unsigned* __restrict__ cursor,
                                                    int* __restrict__ bucket,
                                                    float* __restrict__ g1) {
    const int b = blockIdx.x, t = threadIdx.x;
    if (b < GEMM1_BLOCKS) {
        __shared__ float xs[16 * DIN];  // 8 KB
        const int r0 = b * 16;
        for (int j = t; j < 16 * DIN; j += 256) xs[j] = x[(size_t)r0 * DIN + j];
        __syncthreads();
        const int c = t & 127, rg = (t >> 7) * 8;
        float acc[8] = {};
        for (int k = 0; k < DIN; ++k) {
            float w = W1[k * DHID + c];
#pragma unroll
            for (int r = 0; r < 8; ++r) acc[r] += xs[(rg + r) * DIN + k] * w;
        }
#pragma unroll
        for (int r = 0; r < 8; ++r) g1[(size_t)(r0 + rg + r) * DHID + c] = acc[r];
    } else {
        const int gid = (b - GEMM1_BLOCKS) * 256 + t;
#pragma unroll
        for (int q = 0; q < 3; ++q) {
            int e = gid + q * (FILL_BLOCKS * 256);
            int c = col[e];
            unsigned p = atomicAdd(&cursor[c], 1u);
            if (p < CAP) bucket[(size_t)c * CAP + p] = row[e];
        }
    }
}

// ---------------- K2: gather1 + relu + fused gemm2 ----------------
// wave per node (4/block). float4/lane, 2 rows/instr; index prefetch pipeline.
__global__ __launch_bounds__(256) void k_gather1_gemm2(const float* __restrict__ g1,
                                                       const int* __restrict__ bucket,
                                                       const unsigned* __restrict__ cursor,
                                                       const float* __restrict__ b1,
                                                       const float* __restrict__ W2,
                                                       float* __restrict__ g2) {
    __shared__ float hs[4][DHID];  // 2 KB, wave-private rows
    const int lane = threadIdx.x & 63, wave = threadIdx.x >> 6;
    const int c = blockIdx.x * 4 + wave;
    const unsigned cnt = cursor[c];
    const float dc = rsqrtf((float)cnt + 1.0f);
    const unsigned e = cnt < CAP ? cnt : CAP;
    const f32x4* __restrict__ G4 = (const f32x4*)g1;  // row r = G4[r*32 .. r*32+31]
    const int* __restrict__ bk = bucket + (size_t)c * CAP;
    const int sub = lane >> 5, col4 = lane & 31;

    f32x4 acc = (f32x4){0.f, 0.f, 0.f, 0.f};
    if (sub == 0) acc = G4[(size_t)c * 32 + col4] * dc;  // self-loop term

    unsigned i = 0;
    int pr[4];
    if (i + 8 <= e) {
#pragma unroll
        for (int p = 0; p < 4; ++p) pr[p] = bk[i + 2 * p + sub];
    }
    for (; i + 8 <= e;) {
        int r[4];
#pragma unroll
        for (int p = 0; p < 4; ++p) r[p] = pr[p];
        const unsigned ni = i + 8;
        if (ni + 8 <= e) {
#pragma unroll
            for (int p = 0; p < 4; ++p) pr[p] = bk[ni + 2 * p + sub];
        }
        float d[4];
        f32x4 v[4];
#pragma unroll
        for (int p = 0; p < 4; ++p) {
            d[p] = rsqrtf((float)cursor[r[p]] + 1.0f);
            v[p] = G4[(size_t)r[p] * 32 + col4];
        }
#pragma unroll
        for (int p = 0; p < 4; ++p) acc += v[p] * d[p];
        i = ni;
    }
    for (; i + 2 <= e; i += 2) {
        int rr = bk[i + sub];
        float d = rsqrtf((float)cursor[rr] + 1.0f);
        acc += G4[(size_t)rr * 32 + col4] * d;
    }
    if (i < e && sub == 0) {
        int rr = bk[i];
        float d = rsqrtf((float)cursor[rr] + 1.0f);
        acc += G4[(size_t)rr * 32 + col4] * d;
    }
    acc.x += __shfl_xor(acc.x, 32);
    acc.y += __shfl_xor(acc.y, 32);
    acc.z += __shfl_xor(acc.z, 32);
    acc.w += __shfl_xor(acc.w, 32);

    f32x4 bb = ((const f32x4*)b1)[col4];
    f32x4 o = acc * dc + bb;
    o.x = fmaxf(o.x, 0.f);
    o.y = fmaxf(o.y, 0.f);
    o.z = fmaxf(o.z, 0.f);
    o.w = fmaxf(o.w, 0.f);
    if (sub == 0) ((f32x4*)hs[wave])[col4] = o;

    // gemm2: lane computes output column `lane` (wave-private LDS, no barrier;
    // W2 is 32KB and L1-resident after first pass)
    float a2 = 0.f;
#pragma unroll 8
    for (int k = 0; k < DHID; ++k) a2 += hs[wave][k] * W2[k * DOUT + lane];
    g2[(size_t)c * DOUT + lane] = a2 * dc;
}

// ---------------- K3: gather2 -> latent -> bf16 hi/lo ----------------
// wave per node; float4/lane, 4 rows/instr; index prefetch pipeline.
__global__ __launch_bounds__(256) void k_gather2(const float* __restrict__ g2,
                                                 const int* __restrict__ bucket,
                                                 const unsigned* __restrict__ cursor,
                                                 const float* __restrict__ b2,
                                                 short* __restrict__ H,
                                                 short* __restrict__ Lo) {
    const int lane = threadIdx.x & 63, wave = threadIdx.x >> 6;
    const int c = blockIdx.x * 4 + wave;
    const unsigned cnt = cursor[c];
    const float dc = rsqrtf((float)cnt + 1.0f);
    const unsigned e = cnt < CAP ? cnt : CAP;
    const f32x4* __restrict__ G4 = (const f32x4*)g2;  // row r = G4[r*16 .. r*16+15]
    const int* __restrict__ bk = bucket + (size_t)c * CAP;
    const int sub = lane >> 4, col4 = lane & 15;

    f32x4 acc = (f32x4){0.f, 0.f, 0.f, 0.f};
    if (sub == 0) acc = G4[(size_t)c * 16 + col4];  // self (g2 pre-scaled)

    unsigned i = 0;
    int pr0 = 0, pr1 = 0;
    if (i + 8 <= e) { pr0 = bk[i + sub]; pr1 = bk[i + 4 + sub]; }
    for (; i + 8 <= e;) {
        int r0 = pr0, r1 = pr1;
        const unsigned ni = i + 8;
        if (ni + 8 <= e) { pr0 = bk[ni + sub]; pr1 = bk[ni + 4 + sub]; }
        f32x4 v0 = G4[(size_t)r0 * 16 + col4];
        f32x4 v1 = G4[(size_t)r1 * 16 + col4];
        acc += v0;
        acc += v1;
        i = ni;
    }
    for (; i + 4 <= e; i += 4) {
        int rr = bk[i + sub];
        acc += G4[(size_t)rr * 16 + col4];
    }
    if (i < e) {
        if (sub < (int)(e - i)) {
            int rr = bk[i + sub];
            acc += G4[(size_t)rr * 16 + col4];
        }
    }
    acc.x += __shfl_xor(acc.x, 16); acc.x += __shfl_xor(acc.x, 32);
    acc.y += __shfl_xor(acc.y, 16); acc.y += __shfl_xor(acc.y, 32);
    acc.z += __shfl_xor(acc.z, 16); acc.z += __shfl_xor(acc.z, 32);
    acc.w += __shfl_xor(acc.w, 16); acc.w += __shfl_xor(acc.w, 32);

    if (sub == 0) {
        f32x4 bb = ((const f32x4*)b2)[col4];
        f32x4 v = acc * dc + bb;
        s16x4 h4, l4;
        h4.x = f2bf(v.x); l4.x = f2bf(v.x - bf2f(h4.x));
        h4.y = f2bf(v.y); l4.y = f2bf(v.y - bf2f(h4.y));
        h4.z = f2bf(v.z); l4.z = f2bf(v.z - bf2f(h4.z));
        h4.w = f2bf(v.w); l4.w = f2bf(v.w - bf2f(h4.w));
        ((s16x4*)H)[(size_t)c * 16 + col4] = h4;
        ((s16x4*)Lo)[(size_t)c * 16 + col4] = l4;
    }
}

// ---------------- K4: out = latent @ latent^T, symmetric ----------------
// acc in regs; two 64-row stage+store passes (P = 33.8 KB -> 3 blocks/CU).
#define NTILE 96
#define NPAIR ((NTILE * (NTILE + 1)) / 2)  // 4656
__global__ __launch_bounds__(256) void k_gram(const short* __restrict__ H,
                                              const short* __restrict__ L,
                                              float* __restrict__ out) {
    __shared__ float P[64][132];  // 33.8 KB; rows 16B-aligned
    const int tid  = threadIdx.x;
    const int lane = tid & 63;
    const int wave = tid >> 6;

    // triangular decode: linear Lb -> (bi, bj), bi <= bj
    const int Lb = blockIdx.x;
    int bi = (int)((193.0f - sqrtf(193.0f * 193.0f - 8.0f * (float)Lb)) * 0.5f);
    if (bi < 0) bi = 0;
    if (bi > NTILE - 1) bi = NTILE - 1;
    while (bi * NTILE - (bi * (bi - 1)) / 2 > Lb) --bi;
    while ((bi + 1) * NTILE - ((bi + 1) * bi) / 2 <= Lb) ++bi;
    const int bj = bi + (Lb - (bi * NTILE - (bi * (bi - 1)) / 2));

    const int wm = wave >> 1, wn = wave & 1;
    const int row0 = bi * 128 + wm * 64;
    const int col0 = bj * 128 + wn * 64;
    const int fr = lane & 15;
    const int fk = (lane >> 4) << 3;
    const int crow = (lane >> 4) * 4;
    const bool mirror = (bi != bj);

    bf16x8 aH[4][2], aL[4][2];
#pragma unroll
    for (int m = 0; m < 4; ++m)
#pragma unroll
        for (int k = 0; k < 2; ++k) {
            size_t off = (size_t)(row0 + m * 16 + fr) * DOUT + k * 32 + fk;
            aH[m][k] = *(const bf16x8*)(H + off);
            aL[m][k] = *(const bf16x8*)(L + off);
        }

    f32x4 acc[4][4];  // [n][m]
#pragma unroll
    for (int n = 0; n < 4; ++n)
#pragma unroll
        for (int m = 0; m < 4; ++m) acc[n][m] = (f32x4){0.f, 0.f, 0.f, 0.f};

#pragma unroll
    for (int n = 0; n < 4; ++n) {
        bf16x8 bH[2], bL[2];
#pragma unroll
        for (int k = 0; k < 2; ++k) {
            size_t off = (size_t)(col0 + n * 16 + fr) * DOUT + k * 32 + fk;
            bH[k] = *(const bf16x8*)(H + off);
            bL[k] = *(const bf16x8*)(L + off);
        }
#pragma unroll
        for (int m = 0; m < 4; ++m)
#pragma unroll
            for (int k = 0; k < 2; ++k) {
                acc[n][m] = __builtin_amdgcn_mfma_f32_16x16x32_bf16(aL[m][k], bH[k], acc[n][m], 0, 0, 0);
                acc[n][m] = __builtin_amdgcn_mfma_f32_16x16x32_bf16(aH[m][k], bL[k], acc[n][m], 0, 0, 0);
                acc[n][m] = __builtin_amdgcn_mfma_f32_16x16x32_bf16(aH[m][k], bH[k], acc[n][m], 0, 0, 0);
            }
    }

    const size_t gr0 = (size_t)bi * 128, gc0 = (size_t)bj * 128;
#pragma unroll
    for (int h = 0; h < 2; ++h) {
        __syncthreads();  // protect P reuse across halves
        if (wm == h) {
#pragma unroll
            for (int n = 0; n < 4; ++n)
#pragma unroll
                for (int m = 0; m < 4; ++m)
#pragma unroll
                    for (int j = 0; j < 4; ++j)
                        P[m * 16 + crow + j][wn * 64 + n * 16 + fr] = acc[n][m][j];
        }
        __syncthreads();
        // direct: 64 rows x 128 cols, full 512B rows
#pragma unroll
        for (int it = 0; it < 8; ++it) {
            int idx = it * 256 + tid;
            int r = idx >> 5, c4 = (idx & 31) << 2;
            f32x4 v = *(const f32x4*)&P[r][c4];
            __builtin_nontemporal_store(v, (f32x4*)&out[(gr0 + h * 64 + r) * NN + gc0 + c4]);
        }
        if (mirror) {
            // transposed: 128 rows x 64 cols (256B runs)
#pragma unroll
            for (int it = 0; it < 8; ++it) {
                int idx = it * 256 + tid;
                int r = idx >> 4, c4 = (idx & 15) << 2;
                f32x4 v;
                v.x = P[c4 + 0][r];
                v.y = P[c4 + 1][r];
                v.z = P[c4 + 2][r];
                v.w = P[c4 + 3][r];
                __builtin_nontemporal_store(v, (f32x4*)&out[(gc0 + r) * NN + gr0 + h * 64 + c4]);
            }
        }
    }
}

extern "C" void kernel_launch(void* const* d_in, const int* in_sizes, int n_in,
                              void* d_out, int out_size, void* d_ws, size_t ws_size,
                              hipStream_t stream) {
    const float* x  = (const float*)d_in[0];
    const int*   ei = (const int*)d_in[1];   // row = ei[0..E), col = ei[E..2E)
    const float* W1 = (const float*)d_in[2];
    const float* b1 = (const float*)d_in[3];
    const float* W2 = (const float*)d_in[4];
    const float* b2 = (const float*)d_in[5];
    float* out = (float*)d_out;

    const int* row = ei;
    const int* col = ei + EE;

    // workspace layout (all 16B aligned)
    char* w = (char*)d_ws;
    unsigned* cursor = (unsigned*)w; w += (size_t)NN * 4;
    int*      bucket = (int*)w;      w += (size_t)NN * CAP * 4;   // 4.5 MB
    float*    g1     = (float*)w;    w += (size_t)NN * DHID * 4;  // 6.3 MB
    float*    g2     = (float*)w;    w += (size_t)NN * DOUT * 4;  // 3.1 MB
    short*    latH   = (short*)w;    w += (size_t)NN * DOUT * 2;  // 1.5 MB
    short*    latL   = (short*)w;    w += (size_t)NN * DOUT * 2;  // 1.5 MB

    hipMemsetAsync(cursor, 0, (size_t)NN * 4, stream);

    k_fill_gemm1<<<GEMM1_BLOCKS + FILL_BLOCKS, 256, 0, stream>>>(x, row, col, W1, cursor, bucket, g1);
    k_gather1_gemm2<<<NN / 4, 256, 0, stream>>>(g1, bucket, cursor, b1, W2, g2);
    k_gather2<<<NN / 4, 256, 0, stream>>>(g2, bucket, cursor, b2, latH, latL);

    k_gram<<<NPAIR, 256, 0, stream>>>(latH, latL, out);
}